// Round 1
// 1971.085 us; speedup vs baseline: 1.0882x; 1.0882x over previous
//
#include <hip/hip_runtime.h>
#include <hip/hip_bf16.h>

// ---------------------------------------------------------------------------
// CrossAttention fused pipeline for MI355X (gfx950).
// B=8, N=1024, C=768; 6 stacked tensors of 8192x768.
// R3: XCD-chunked block swizzle on all GEMMs (panel reuse within one L2);
//     blocked fragment-native D layout (ushort8 coalesced stores) + matching
//     wsum reader.
// ---------------------------------------------------------------------------

typedef short bshort8 __attribute__((ext_vector_type(8)));
typedef unsigned short u16x8 __attribute__((ext_vector_type(8)));
typedef float f32x4  __attribute__((ext_vector_type(4)));

#define AS1 __attribute__((address_space(1)))
#define AS3 __attribute__((address_space(3)))

#define B_   8
#define N_   1024
#define C_   768
#define MT   8192      /* B_*N_ rows per tensor  */
#define M6   49152     /* 6 tensors stacked      */

// ---- workspace layout (bytes) ----
#define OFF_QKNORM   0ull            /* 49152 f32 row sqnorms of qk            */
#define OFF_MAPS     196608ull       /* 49152 f32 attention maps (6 x 8192)    */
#define OFF_STATS    393216ull       /* 15 slabs x 4 x 8192 f32 row/col sums   */
#define OFF_WBUF     2359296ull      /* 15 slabs x 2 x 8192 f32 weights        */
#define OFF_MM       3342336ull      /* 15 min + 15 max (u32 bits)             */
#define MEMSET_BYTES 3342464ull
#define OFF_WTPROJ   3342592ull      /* 1536x768 bf16 (proj_W^T)               */
#define OFF_WTFC1    5701888ull      /* 3072x768 bf16 (fc1_W^T)                */
#define OFF_WTFC2    10420480ull     /* 768x3072 bf16 (fc2_W^T)                */
#define OFF_LNBF     15139072ull     /* 49152x768 bf16 LN1 output              */
#define OFF_QKBF     90636544ull     /* 49152x768 bf16 qk (later reused as xh) */
#define OFF_XHBF     OFF_QKBF        /* alias: qk dead before combine          */
#define OFF_VBF      166134016ull    /* 49152x768 bf16 v                       */
#define OFF_DBUF     241631488ull    /* 8 slabs x 8x1024x1024 bf16 D (134 MB)  */
#define OFF_H1BF     OFF_DBUF        /* alias: FFN intermediate (151 MB chunk) */
// peak: 241631488 + 150994944 = 392,626,432 bytes (<= proven 409 MB ws)

// slab tables: D[i over SU][j over SV]; 0..2 are S_p slabs, 3..14 cross slabs.
// TA = type of use-A (weights over rows -> m[SV]); TB = use-B (cols -> m[SU]).
// type 0 = S_p (coef -1, offset=max); 1 = alpha branch; 2 = (1-alpha) branch.
__constant__ int cSU[15] = {1,3,5, 2,3,4,5, 2,3,4,5, 4,5,4,5};
__constant__ int cSV[15] = {0,2,4, 0,0,0,0, 1,1,1,1, 2,2,3,3};
__constant__ int cTA[15] = {0,0,0, 1,1,2,2, 1,1,2,2, 2,2,2,2};
__constant__ int cTB[15] = {0,0,0, 1,1,1,1, 1,1,1,1, 2,2,2,2};

__device__ __forceinline__ void gll16(const void* g, void* l) {
    __builtin_amdgcn_global_load_lds((const AS1 unsigned int*)g,
                                     (AS3 unsigned int*)l, 16, 0, 0);
}
__device__ __forceinline__ unsigned short f2bu(float v) {
    __hip_bfloat16 h = __float2bfloat16(v);
    return *reinterpret_cast<unsigned short*>(&h);
}
__device__ __forceinline__ float bu2f(unsigned short u) {
    __hip_bfloat16 h;
    *reinterpret_cast<unsigned short*>(&h) = u;
    return __bfloat162float(h);
}
// XCD-chunked bijective swizzle: dispatch order round-robins XCDs; give each
// XCD a contiguous chunk of the work so panel-sharing blocks share one L2.
// Requires nwg % 8 == 0 (all call sites: 4096/3584/4608/1152).
__device__ __forceinline__ int xcd_swz(int flat, int nwg) {
    return (flat & 7) * (nwg >> 3) + (flat >> 3);
}

// ---------------------------------------------------------------------------
// 128x128 bf16 NT GEMM core, software-pipelined:
// ping-pong LDS (2 x (A 8K | B 8K)); per K-iter: ONE barrier, then async
// prefetch of tile k+1 into the other buffer overlaps ds_read+MFMA of tile k.
// 256 threads = 4 waves in 2x2; each wave 64x64 via 4x4 mfma_16x16x32_bf16.
// ---------------------------------------------------------------------------
__device__ __forceinline__ void gemm_core(const __hip_bfloat16* __restrict__ A,
                                          const __hip_bfloat16* __restrict__ Bt,
                                          int lda, int ldb, int kIters,
                                          char* smem, f32x4 acc[4][4])
{
    const int tid  = threadIdx.x;
    const int w    = tid >> 6;
    const int L    = tid & 63;
    const int srow = L >> 2;                       // 0..15
    const int schunk = (L & 3) ^ ((L >> 3) & 3);   // swizzled 16B k-chunk

    const char* ga0 = (const char*)(A  + (size_t)(32*w      + srow) * lda + schunk*8);
    const char* ga1 = (const char*)(A  + (size_t)(32*w + 16 + srow) * lda + schunk*8);
    const char* gb0 = (const char*)(Bt + (size_t)(32*w      + srow) * ldb + schunk*8);
    const char* gb1 = (const char*)(Bt + (size_t)(32*w + 16 + srow) * ldb + schunk*8);
    const int la0 = (32*w)*64;
    const int la1 = (32*w+16)*64;
    const int lb0 = 8192 + (32*w)*64;
    const int lb1 = 8192 + (32*w+16)*64;

    const int m = L & 15, q = L >> 4;
    const int wr = (w >> 1) * 64, wc = (w & 1) * 64;
    const int roff = 16 * (q ^ ((m >> 1) & 3));
    int ra[4], rb[4];
#pragma unroll
    for (int s = 0; s < 4; ++s) {
        ra[s] = (wr + 16*s + m) * 64 + roff;
        rb[s] = 8192 + (wc + 16*s + m) * 64 + roff;
    }
    f32x4 z = {0.f, 0.f, 0.f, 0.f};
#pragma unroll
    for (int s = 0; s < 4; ++s)
#pragma unroll
        for (int t = 0; t < 4; ++t) acc[s][t] = z;

    char* b0 = smem;
    char* b1 = smem + 16384;

    // prologue: tile 0 -> b0
    gll16(ga0, b0 + la0); gll16(ga1, b0 + la1);
    gll16(gb0, b0 + lb0); gll16(gb1, b0 + lb1);
    ga0 += 64; ga1 += 64; gb0 += 64; gb1 += 64;

    auto step = [&](char* cur, char* nxt, bool last) {
        __syncthreads();                 // tile in `cur` ready; prior reads of `nxt` done
        if (!last) {
            gll16(ga0, nxt + la0); gll16(ga1, nxt + la1);
            gll16(gb0, nxt + lb0); gll16(gb1, nxt + lb1);
            ga0 += 64; ga1 += 64; gb0 += 64; gb1 += 64;
        }
        bshort8 af[4], bfr[4];
#pragma unroll
        for (int s = 0; s < 4; ++s) af[s]  = *(const bshort8*)(cur + ra[s]);
#pragma unroll
        for (int t = 0; t < 4; ++t) bfr[t] = *(const bshort8*)(cur + rb[t]);
#pragma unroll
        for (int s = 0; s < 4; ++s)
#pragma unroll
            for (int t = 0; t < 4; ++t)
                acc[s][t] = __builtin_amdgcn_mfma_f32_16x16x32_bf16(af[s], bfr[t], acc[s][t], 0, 0, 0);
    };

    for (int kt = 0; kt < kIters; kt += 2) {
        step(b0, b1, false);
        step(b1, b0, kt + 2 >= kIters);
    }
}

// ---------------------------------------------------------------------------
// transpose f32 (R x C) -> bf16 (C x R)
// ---------------------------------------------------------------------------
__global__ __launch_bounds__(256) void transpose_conv(const float* __restrict__ in,
                                                      __hip_bfloat16* __restrict__ out,
                                                      int R, int C)
{
    __shared__ float tile[32][33];
    int bx = blockIdx.x * 32, by = blockIdx.y * 32;
    int tx = threadIdx.x, ty = threadIdx.y;
#pragma unroll
    for (int i = 0; i < 32; i += 8)
        tile[ty + i][tx] = in[(size_t)(by + ty + i) * C + bx + tx];
    __syncthreads();
#pragma unroll
    for (int i = 0; i < 32; i += 8)
        out[(size_t)(bx + ty + i) * R + by + tx] = __float2bfloat16(tile[tx][ty + i]);
}

__global__ void init_mm(unsigned int* mm)
{
    int i = threadIdx.x;
    if (i < 15) { mm[i] = 0x7f800000u; mm[15 + i] = 0u; }
}

// ---------------------------------------------------------------------------
// LN1: wave per row, float4 loads, ushort4 bf16 stores
// ---------------------------------------------------------------------------
__global__ __launch_bounds__(256) void ln1_kernel(const float* __restrict__ anchor,
                                                  const float* __restrict__ positive,
                                                  const float* __restrict__ neg1,
                                                  const float* __restrict__ neg2,
                                                  const float* __restrict__ w1,
                                                  const float* __restrict__ b1,
                                                  __hip_bfloat16* __restrict__ lnbf)
{
    int w = threadIdx.x >> 6, L = threadIdx.x & 63;
    int r = blockIdx.x * 4 + w;
    int t = r >> 13, within = r & 8191;
    const float* src;
    if      (t == 0) src = anchor   + (size_t)within * C_;
    else if (t == 1) src = positive + (size_t)within * C_;
    else if (t <  4) src = neg1 + ((size_t)(t - 2) * MT + within) * C_;
    else             src = neg2 + ((size_t)(t - 4) * MT + within) * C_;
    float4 x[3]; float s = 0.f, sq = 0.f;
#pragma unroll
    for (int j = 0; j < 3; ++j) {
        x[j] = *(const float4*)(src + 4 * L + 256 * j);
        s  += x[j].x + x[j].y + x[j].z + x[j].w;
        sq += x[j].x*x[j].x + x[j].y*x[j].y + x[j].z*x[j].z + x[j].w*x[j].w;
    }
#pragma unroll
    for (int o = 1; o < 64; o <<= 1) { s += __shfl_xor(s, o, 64); sq += __shfl_xor(sq, o, 64); }
    float mu  = s * (1.f / 768.f);
    float var = sq * (1.f / 768.f) - mu * mu;
    float rs  = rsqrtf(var + 1e-5f);
    __hip_bfloat16* dst = lnbf + (size_t)r * C_;
#pragma unroll
    for (int j = 0; j < 3; ++j) {
        int c = 4 * L + 256 * j;
        float4 wv = *(const float4*)(w1 + c);
        float4 bv = *(const float4*)(b1 + c);
        ushort4 o;
        o.x = f2bu((x[j].x - mu) * rs * wv.x + bv.x);
        o.y = f2bu((x[j].y - mu) * rs * wv.y + bv.y);
        o.z = f2bu((x[j].z - mu) * rs * wv.z + bv.z);
        o.w = f2bu((x[j].w - mu) * rs * wv.w + bv.w);
        *(ushort4*)(dst + c) = o;
    }
}

// ---------------------------------------------------------------------------
// proj GEMM: ln_bf (49152x768) @ Wt_proj^T -> qk_bf | v_bf (+bias, +qknorm)
// grid flattened (12 x 384) with XCD swizzle: each XCD gets contiguous
// row-panel ranges -> A panel fetched into ONE L2 instead of all eight.
// ---------------------------------------------------------------------------
__global__ __launch_bounds__(256) void gemm_proj(const __hip_bfloat16* __restrict__ A,
                                                 const __hip_bfloat16* __restrict__ Wt,
                                                 const float* __restrict__ bias,
                                                 __hip_bfloat16* __restrict__ qkbf,
                                                 __hip_bfloat16* __restrict__ vbf,
                                                 float* __restrict__ qknorm)
{
    __shared__ __align__(16) char smem[32768];
    int flat = blockIdx.x + 12 * blockIdx.y;
    int sf   = xcd_swz(flat, 12 * 384);
    int bx = sf % 12, by = sf / 12;
    f32x4 acc[4][4];
    gemm_core(A + (size_t)by * 128 * C_, Wt + (size_t)bx * 128 * C_,
              C_, C_, 24, smem, acc);
    int tid = threadIdx.x, w = tid >> 6, L = tid & 63, m = L & 15, q = L >> 4;
    int rowBase = by * 128 + (w >> 1) * 64;
    int colBase = bx * 128 + (w & 1) * 64;
    bool isQK = (bx < 6);
#pragma unroll
    for (int s = 0; s < 4; ++s) {
#pragma unroll
        for (int r = 0; r < 4; ++r) {
            int row = rowBase + 16 * s + 4 * q + r;
            float sqsum = 0.f;
#pragma unroll
            for (int t = 0; t < 4; ++t) {
                int col = colBase + 16 * t + m;
                float val = acc[s][t][r] + bias[col];
                if (isQK) {
                    qkbf[(size_t)row * C_ + col] = __float2bfloat16(val);
                    sqsum += val * val;
                } else {
                    vbf[(size_t)row * C_ + (col - C_)] = __float2bfloat16(val);
                }
            }
            if (isQK) {
#pragma unroll
                for (int o = 1; o < 16; o <<= 1) sqsum += __shfl_xor(sqsum, o, 64);
                if (m == 0) atomicAdd(qknorm + row, sqsum);
            }
        }
    }
}

// ---------------------------------------------------------------------------
// gram/D kernel: D = sqrt(max(na+nb-2*G,1e-12)); stores D in a BLOCKED
// fragment-native layout (see below) + fused pass-1 reductions (row/col sums
// of D and D^2 in f32, global min/max).
// grid (64 tiles, 8 batches, nslabs), XCD-swizzled so each (slab,batch)
// 64-tile group (A+B panel set = 3.2 MB) stays in one XCD's L2.
//
// Blocked D layout (bf16 elements), chosen so epilogue stores and wsum loads
// are 16B/lane fully-coalesced:
//   base(z,b,tile,w) = z*8388608 + b*2^20 + tile*16384 + w*4096
//   within wave chunk: elem = (s*2+tp)*512 + m*32 + q*8 + (t&1)*4 + r
//   where value at (s,t,q,m,r) is D[row,col],
//   row = ti*128 + (w>>1)*64 + 16s + 4q + r, col = tj*128 + (w&1)*64 + 16t + m.
// ---------------------------------------------------------------------------
__global__ __launch_bounds__(256) void gram_kernel(const __hip_bfloat16* __restrict__ qkbf,
                                                   const float* __restrict__ qknorm,
                                                   __hip_bfloat16* __restrict__ Dbuf,
                                                   float* __restrict__ stats,
                                                   unsigned int* __restrict__ mm,
                                                   int sb)
{
    __shared__ __align__(16) char smem[32768];
    int flat = blockIdx.x + 64 * blockIdx.y + 512 * blockIdx.z;
    int nwg  = 512 * gridDim.z;
    int sf   = xcd_swz(flat, nwg);
    int tile = sf & 63;
    int b    = (sf >> 6) & 7;
    int z    = sf >> 9;
    int slab = sb + z;
    int ti = tile >> 3, tj = tile & 7;
    int u = cSU[slab], v = cSV[slab];

    const __hip_bfloat16* Ab = qkbf + (size_t)(u * MT + b * N_ + ti * 128) * C_;
    const __hip_bfloat16* Bb = qkbf + (size_t)(v * MT + b * N_ + tj * 128) * C_;
    f32x4 acc[4][4];
    gemm_core(Ab, Bb, C_, C_, 24, smem, acc);

    int tid = threadIdx.x, w = tid >> 6, L = tid & 63, m = L & 15, q = L >> 4;
    int rowBase = ti * 128 + (w >> 1) * 64;
    int colBase = tj * 128 + (w & 1) * 64;
    const float* nu = qknorm + u * MT + b * N_;
    const float* nv = qknorm + v * MT + b * N_;
    float nbv[4];
#pragma unroll
    for (int t = 0; t < 4; ++t) nbv[t] = nv[colBase + 16 * t + m];

    unsigned short* Dc = (unsigned short*)Dbuf + (size_t)z * 8388608ull
                         + ((size_t)b << 20) + (size_t)tile * 16384 + w * 4096;
    float* rs1 = stats + (size_t)slab * 32768;
    float* rs2 = rs1 + 8192;
    float* cs1 = rs1 + 16384;
    float* cs2 = rs1 + 24576;

    float dmin = 3.0e38f, dmax = 0.f;
    float col1[4] = {0.f,0.f,0.f,0.f}, col2[4] = {0.f,0.f,0.f,0.f};
#pragma unroll
    for (int s = 0; s < 4; ++s) {
        float na[4];
#pragma unroll
        for (int r = 0; r < 4; ++r) na[r] = nu[rowBase + 16 * s + 4 * q + r];
        float dv[4][4];          // [t][r]
        float h1v[4] = {0.f,0.f,0.f,0.f}, h2v[4] = {0.f,0.f,0.f,0.f};
#pragma unroll
        for (int t = 0; t < 4; ++t) {
#pragma unroll
            for (int r = 0; r < 4; ++r) {
                float d = sqrtf(fmaxf(na[r] + nbv[t] - 2.f * acc[s][t][r], 1e-12f));
                dv[t][r] = d;
                h1v[r] += d; h2v[r] += d * d;
                col1[t] += d; col2[t] += d * d;
                dmin = fminf(dmin, d); dmax = fmaxf(dmax, d);
            }
        }
        // blocked, fully-coalesced D store: 2 x ushort8 per s (16B/lane)
#pragma unroll
        for (int tp = 0; tp < 2; ++tp) {
            u16x8 pk;
#pragma unroll
            for (int e = 0; e < 8; ++e)
                pk[e] = f2bu(dv[2 * tp + (e >> 2)][e & 3]);
            *(u16x8*)(Dc + (s * 2 + tp) * 512 + m * 32 + q * 8) = pk;
        }
        // row sums (reduce over m within each 16-lane group)
#pragma unroll
        for (int r = 0; r < 4; ++r) {
            float h1 = h1v[r], h2 = h2v[r];
#pragma unroll
            for (int o = 1; o < 16; o <<= 1) { h1 += __shfl_xor(h1, o, 64); h2 += __shfl_xor(h2, o, 64); }
            if (m == 0) {
                int row = rowBase + 16 * s + 4 * q + r;
                atomicAdd(rs1 + b * N_ + row, h1);
                atomicAdd(rs2 + b * N_ + row, h2);
            }
        }
    }
#pragma unroll
    for (int t = 0; t < 4; ++t) {
        float c1 = col1[t], c2 = col2[t];
        c1 += __shfl_xor(c1, 16, 64); c1 += __shfl_xor(c1, 32, 64);
        c2 += __shfl_xor(c2, 16, 64); c2 += __shfl_xor(c2, 32, 64);
        if (q == 0) {
            int col = colBase + 16 * t + m;
            atomicAdd(cs1 + b * N_ + col, c1);
            atomicAdd(cs2 + b * N_ + col, c2);
        }
    }
#pragma unroll
    for (int o = 1; o < 64; o <<= 1) {
        dmin = fminf(dmin, __shfl_xor(dmin, o, 64));
        dmax = fmaxf(dmax, __shfl_xor(dmax, o, 64));
    }
    if (L == 0) {
        atomicMin(mm + slab, __float_as_uint(dmin));
        atomicMax(mm + 15 + slab, __float_as_uint(dmax));
    }
}

// ---------------------------------------------------------------------------
// weights kernel: per (slab-use, batch): w' = cf / max(||D row - off||,1e-12),
// plus adds the -off*sum(w') constant into the destination map.
// grid (2*nslabs, 8)
// ---------------------------------------------------------------------------
__global__ __launch_bounds__(256) void weights_kernel(const float* __restrict__ stats,
                                                      const unsigned int* __restrict__ mm,
                                                      float* __restrict__ wbuf,
                                                      float* __restrict__ maps,
                                                      const float* __restrict__ theta,
                                                      const float* __restrict__ alpha,
                                                      int sb)
{
    int job = blockIdx.x, b = blockIdx.y;
    int slab = sb + (job >> 1);
    int useB = job & 1;                      // 0: rows axis, 1: cols axis
    const float* s1 = stats + (size_t)slab * 32768 + useB * 16384;
    const float* s2 = s1 + 8192;
    int type = useB ? cTB[slab] : cTA[slab];
    int dst  = useB ? cSU[slab] : cSV[slab];
    float off = (type == 0) ? __uint_as_float(mm[15 + slab]) : __uint_as_float(mm[slab]);
    float k  = tanhf(theta[0]) + 1.0f;
    float al = 1.0f / (1.0f + expf(-alpha[0]));
    float cf = (type == 0) ? -1.0f : ((type == 1) ? 0.5f * k * al : 0.5f * k * (1.0f - al));
    float* wout = wbuf + (size_t)slab * 16384 + useB * 8192 + b * N_;

    float sumw = 0.f;
    for (int i = threadIdx.x; i < N_; i += 256) {
        float a1 = s1[b * N_ + i], a2 = s2[b * N_ + i];
        float nrm2  = fmaxf(a2 - 2.f * off * a1 + (float)N_ * off * off, 0.f);
        float denom = fmaxf(sqrtf(nrm2), 1e-12f);
        float wv = cf / denom;
        wout[i] = wv;
        sumw += wv;
    }
    int w = threadIdx.x >> 6, L = threadIdx.x & 63;
#pragma unroll
    for (int o = 1; o < 64; o <<= 1) sumw += __shfl_xor(sumw, o, 64);
    __shared__ float red[4];
    if (L == 0) red[w] = sumw;
    __syncthreads();
    float tot = red[0] + red[1] + red[2] + red[3];
    float Cb = -off * tot;
    for (int j = threadIdx.x; j < N_; j += 256)
        atomicAdd(maps + (size_t)dst * MT + b * N_ + j, Cb);
}

// ---------------------------------------------------------------------------
// weighted-sum pass over blocked bf16 D: each 128x128 tile read once;
//   m[SU][row] += sum_j wCol[j]*D[row,j], m[SV][col] += sum_i wRow[i]*D[i,col]
// Reads the fragment-native layout written by gram_kernel (16B/lane loads).
// grid (64 tiles, 8 batches, nslabs)
// ---------------------------------------------------------------------------
__global__ __launch_bounds__(256) void wsum_kernel(const __hip_bfloat16* __restrict__ Dbuf,
                                                   const float* __restrict__ wbuf,
                                                   float* __restrict__ maps,
                                                   int sb)
{
    int z = blockIdx.z, slab = sb + z, b = blockIdx.y;
    int tile = blockIdx.x;
    int ti = tile >> 3, tj = tile & 7;
    int u = cSU[slab], v = cSV[slab];
    int tid = threadIdx.x, w = tid >> 6, L = tid & 63, m = L & 15, q = L >> 4;
    const unsigned short* Dc = (const unsigned short*)Dbuf + (size_t)z * 8388608ull
                               + ((size_t)b << 20) + (size_t)tile * 16384 + w * 4096;
    const float* wr = wbuf + (size_t)slab * 16384 + b * N_ + ti * 128;
    const float* wc = wbuf + (size_t)slab * 16384 + 8192 + b * N_ + tj * 128;

    __shared__ float swr[128], swc[128];
    if (threadIdx.x < 128) swr[threadIdx.x] = wr[threadIdx.x];
    else                   swc[threadIdx.x - 128] = wc[threadIdx.x - 128];
    __syncthreads();

    int wrbase = (w >> 1) * 64, wcbase = (w & 1) * 64;
    float wc1[4];
#pragma unroll
    for (int t = 0; t < 4; ++t) wc1[t] = swc[wcbase + 16 * t + m];
    float wr4[4][4];
#pragma unroll
    for (int s = 0; s < 4; ++s)
#pragma unroll
        for (int r = 0; r < 4; ++r) wr4[s][r] = swr[wrbase + 16 * s + 4 * q + r];

    float rowacc[4][4];
#pragma unroll
    for (int s = 0; s < 4; ++s)
#pragma unroll
        for (int r = 0; r < 4; ++r) rowacc[s][r] = 0.f;
    float colacc[4] = {0.f,0.f,0.f,0.f};

#pragma unroll
    for (int s = 0; s < 4; ++s) {
#pragma unroll
        for (int tp = 0; tp < 2; ++tp) {
            u16x8 d8 = *(const u16x8*)(Dc + (s * 2 + tp) * 512 + m * 32 + q * 8);
#pragma unroll
            for (int e = 0; e < 8; ++e) {
                int t = 2 * tp + (e >> 2), r = e & 3;
                float d = bu2f(d8[e]);
                rowacc[s][r] += wc1[t] * d;
                colacc[t]    += wr4[s][r] * d;
            }
        }
    }
    // rows: reduce over m (16 lanes per q-group), atomic at m==0
#pragma unroll
    for (int s = 0; s < 4; ++s)
#pragma unroll
        for (int r = 0; r < 4; ++r) {
            float h = rowacc[s][r];
#pragma unroll
            for (int o = 1; o < 16; o <<= 1) h += __shfl_xor(h, o, 64);
            if (m == 0)
                atomicAdd(maps + (size_t)u * MT + b * N_ + ti * 128 + wrbase + 16 * s + 4 * q + r, h);
        }
    // cols: reduce over q (xor 16, 32), atomic at q==0
#pragma unroll
    for (int t = 0; t < 4; ++t) {
        float c = colacc[t];
        c += __shfl_xor(c, 16, 64); c += __shfl_xor(c, 32, 64);
        if (q == 0)
            atomicAdd(maps + (size_t)v * MT + b * N_ + tj * 128 + wcbase + 16 * t + m, c);
    }
}

// ---------------------------------------------------------------------------
// combine + LN2: x = m*v + ln (t<2) or m*v*ln (t>=2); writes x (f32, d_out)
// and LN2(x) as bf16 for the FFN. Vectorized 4-wide.
// ---------------------------------------------------------------------------
__global__ __launch_bounds__(256) void combine_ln2(const float* __restrict__ maps,
                                                   const __hip_bfloat16* __restrict__ vbf,
                                                   const __hip_bfloat16* __restrict__ lnbf,
                                                   const float* __restrict__ w2,
                                                   const float* __restrict__ b2,
                                                   float* __restrict__ dout,
                                                   __hip_bfloat16* __restrict__ xhbf)
{
    int w = threadIdx.x >> 6, L = threadIdx.x & 63;
    int r = blockIdx.x * 4 + w;
    int t = r >> 13;
    float mv = maps[r];
    const __hip_bfloat16* vp = vbf + (size_t)r * C_;
    const __hip_bfloat16* lp = lnbf + (size_t)r * C_;
    float x[12]; float s = 0.f, sq = 0.f;
#pragma unroll
    for (int j = 0; j < 3; ++j) {
        int c = 4 * L + 256 * j;
        ushort4 vv = *(const ushort4*)(vp + c);
        ushort4 ll = *(const ushort4*)(lp + c);
        float xv[4];
        xv[0] = (t < 2) ? (mv * bu2f(vv.x) + bu2f(ll.x)) : (mv * bu2f(vv.x) * bu2f(ll.x));
        xv[1] = (t < 2) ? (mv * bu2f(vv.y) + bu2f(ll.y)) : (mv * bu2f(vv.y) * bu2f(ll.y));
        xv[2] = (t < 2) ? (mv * bu2f(vv.z) + bu2f(ll.z)) : (mv * bu2f(vv.z) * bu2f(ll.z));
        xv[3] = (t < 2) ? (mv * bu2f(vv.w) + bu2f(ll.w)) : (mv * bu2f(vv.w) * bu2f(ll.w));
        float4 xo = {xv[0], xv[1], xv[2], xv[3]};
        *(float4*)(dout + (size_t)r * C_ + c) = xo;
#pragma unroll
        for (int e = 0; e < 4; ++e) { x[4*j+e] = xv[e]; s += xv[e]; sq += xv[e]*xv[e]; }
    }
#pragma unroll
    for (int o = 1; o < 64; o <<= 1) { s += __shfl_xor(s, o, 64); sq += __shfl_xor(sq, o, 64); }
    float mu  = s * (1.f / 768.f);
    float var = sq * (1.f / 768.f) - mu * mu;
    float rs  = rsqrtf(var + 1e-5f);
    __hip_bfloat16* dst = xhbf + (size_t)r * C_;
#pragma unroll
    for (int j = 0; j < 3; ++j) {
        int c = 4 * L + 256 * j;
        float4 wv = *(const float4*)(w2 + c);
        float4 bv = *(const float4*)(b2 + c);
        ushort4 o;
        o.x = f2bu((x[4*j+0] - mu) * rs * wv.x + bv.x);
        o.y = f2bu((x[4*j+1] - mu) * rs * wv.y + bv.y);
        o.z = f2bu((x[4*j+2] - mu) * rs * wv.z + bv.z);
        o.w = f2bu((x[4*j+3] - mu) * rs * wv.w + bv.w);
        *(ushort4*)(dst + c) = o;
    }
}

// ---------------------------------------------------------------------------
// FFN1: xh @ fc1^T + b -> gelu(exact) -> bf16  (XCD-swizzled)
// ---------------------------------------------------------------------------
__global__ __launch_bounds__(256) void gemm_ffn1(const __hip_bfloat16* __restrict__ A,
                                                 const __hip_bfloat16* __restrict__ Wt,
                                                 const float* __restrict__ bias,
                                                 __hip_bfloat16* __restrict__ h1)
{
    __shared__ __align__(16) char smem[32768];
    int flat = blockIdx.x + 24 * blockIdx.y;
    int sf   = xcd_swz(flat, 24 * 192);
    int bx = sf % 24, by = sf / 24;
    f32x4 acc[4][4];
    gemm_core(A + (size_t)by * 128 * C_, Wt + (size_t)bx * 128 * C_,
              C_, C_, 24, smem, acc);
    int tid = threadIdx.x, w = tid >> 6, L = tid & 63, m = L & 15, q = L >> 4;
    int rowBase = by * 128 + (w >> 1) * 64;
    int colBase = bx * 128 + (w & 1) * 64;
#pragma unroll
    for (int s = 0; s < 4; ++s)
#pragma unroll
        for (int r = 0; r < 4; ++r) {
            int row = rowBase + 16 * s + 4 * q + r;
#pragma unroll
            for (int t = 0; t < 4; ++t) {
                int col = colBase + 16 * t + m;
                float val = acc[s][t][r] + bias[col];
                float ge  = 0.5f * val * (1.0f + erff(val * 0.70710678118654752f));
                h1[(size_t)row * 3072 + col] = __float2bfloat16(ge);
            }
        }
}

// ---------------------------------------------------------------------------
// FFN2: h1 @ fc2^T + b, accumulated into d_out (residual already there)
// ---------------------------------------------------------------------------
__global__ __launch_bounds__(256) void gemm_ffn2(const __hip_bfloat16* __restrict__ A,
                                                 const __hip_bfloat16* __restrict__ Wt,
                                                 const float* __restrict__ bias,
                                                 float* __restrict__ out)
{
    __shared__ __align__(16) char smem[32768];
    int flat = blockIdx.x + 6 * blockIdx.y;
    int sf   = xcd_swz(flat, 6 * 192);
    int bx = sf % 6, by = sf / 6;
    f32x4 acc[4][4];
    gemm_core(A + (size_t)by * 128 * 3072, Wt + (size_t)bx * 128 * 3072,
              3072, 3072, 96, smem, acc);
    int tid = threadIdx.x, w = tid >> 6, L = tid & 63, m = L & 15, q = L >> 4;
    int rowBase = by * 128 + (w >> 1) * 64;
    int colBase = bx * 128 + (w & 1) * 64;
#pragma unroll
    for (int s = 0; s < 4; ++s)
#pragma unroll
        for (int r = 0; r < 4; ++r) {
            int row = rowBase + 16 * s + 4 * q + r;
#pragma unroll
            for (int t = 0; t < 4; ++t) {
                int col = colBase + 16 * t + m;
                size_t idx = (size_t)row * C_ + col;
                out[idx] = out[idx] + acc[s][t][r] + bias[col];
            }
        }
}

// ---------------------------------------------------------------------------
extern "C" void kernel_launch(void* const* d_in, const int* in_sizes, int n_in,
                              void* d_out, int out_size, void* d_ws, size_t ws_size,
                              hipStream_t stream)
{
    (void)in_sizes; (void)n_in; (void)out_size; (void)ws_size;
    const float* anchor   = (const float*)d_in[0];
    const float* positive = (const float*)d_in[1];
    const float* neg1     = (const float*)d_in[2];
    const float* neg2     = (const float*)d_in[3];
    const float* n1w      = (const float*)d_in[4];
    const float* n1b      = (const float*)d_in[5];
    const float* n2w      = (const float*)d_in[6];
    const float* n2b      = (const float*)d_in[7];
    const float* projW    = (const float*)d_in[8];
    const float* projb    = (const float*)d_in[9];
    const float* fc1W     = (const float*)d_in[10];
    const float* fc1b     = (const float*)d_in[11];
    const float* fc2W     = (const float*)d_in[12];
    const float* fc2b     = (const float*)d_in[13];
    const float* theta    = (const float*)d_in[14];
    const float* alpha    = (const float*)d_in[15];
    float* dout = (float*)d_out;

    char* ws = (char*)d_ws;
    float*          qknorm = (float*)(ws + OFF_QKNORM);
    float*          maps   = (float*)(ws + OFF_MAPS);
    float*          stats  = (float*)(ws + OFF_STATS);
    float*          wbuf   = (float*)(ws + OFF_WBUF);
    unsigned int*   mm     = (unsigned int*)(ws + OFF_MM);
    __hip_bfloat16* WtProj = (__hip_bfloat16*)(ws + OFF_WTPROJ);
    __hip_bfloat16* WtFc1  = (__hip_bfloat16*)(ws + OFF_WTFC1);
    __hip_bfloat16* WtFc2  = (__hip_bfloat16*)(ws + OFF_WTFC2);
    __hip_bfloat16* lnbf   = (__hip_bfloat16*)(ws + OFF_LNBF);
    __hip_bfloat16* qkbf   = (__hip_bfloat16*)(ws + OFF_QKBF);
    __hip_bfloat16* xhbf   = (__hip_bfloat16*)(ws + OFF_XHBF);
    __hip_bfloat16* vbf    = (__hip_bfloat16*)(ws + OFF_VBF);
    __hip_bfloat16* Dbuf   = (__hip_bfloat16*)(ws + OFF_DBUF);
    __hip_bfloat16* h1bf   = (__hip_bfloat16*)(ws + OFF_H1BF);

    hipMemsetAsync(ws, 0, MEMSET_BYTES, stream);
    init_mm<<<1, 64, 0, stream>>>(mm);

    transpose_conv<<<dim3(48, 24), dim3(32, 8), 0, stream>>>(projW, WtProj, 768, 1536);
    transpose_conv<<<dim3(96, 24), dim3(32, 8), 0, stream>>>(fc1W,  WtFc1,  768, 3072);
    transpose_conv<<<dim3(24, 96), dim3(32, 8), 0, stream>>>(fc2W,  WtFc2,  3072, 768);

    ln1_kernel<<<12288, 256, 0, stream>>>(anchor, positive, neg1, neg2, n1w, n1b, lnbf);

    gemm_proj<<<dim3(12, 384), 256, 0, stream>>>(lnbf, WtProj, projb, qkbf, vbf, qknorm);

    for (int g = 0; g < 2; ++g) {
        int sb = g * 8;
        int ns = g ? 7 : 8;
        gram_kernel<<<dim3(64, 8, ns), 256, 0, stream>>>(qkbf, qknorm, Dbuf, stats, mm, sb);
        weights_kernel<<<dim3(2 * ns, 8), 256, 0, stream>>>(stats, mm, wbuf, maps, theta, alpha, sb);
        wsum_kernel<<<dim3(64, 8, ns), 256, 0, stream>>>(Dbuf, wbuf, maps, sb);
    }

    combine_ln2<<<12288, 256, 0, stream>>>(maps, vbf, lnbf, n2w, n2b, dout, xhbf);

    for (int ch = 0; ch < 2; ++ch) {
        size_t ro = (size_t)ch * 24576;
        gemm_ffn1<<<dim3(24, 192), 256, 0, stream>>>(xhbf + ro * C_, WtFc1, fc1b, h1bf);
        gemm_ffn2<<<dim3(6, 192), 256, 0, stream>>>(h1bf, WtFc2, fc2b, dout + ro * C_);
    }
}

// Round 2
// 1719.565 us; speedup vs baseline: 1.2474x; 1.1463x over previous
//
#include <hip/hip_runtime.h>
#include <hip/hip_bf16.h>

// ---------------------------------------------------------------------------
// CrossAttention fused pipeline for MI355X (gfx950).
// B=8, N=1024, C=768; 6 stacked tensors of 8192x768.
// R4: all GEMMs moved to a 256x256xBK64 8-wave 2-phase core (drain amortized
//     over 64 MFMA/tile instead of 16). D blocked layout contract preserved,
//     wsum/weights/LN/combine unchanged. XCD swizzle kept.
// ---------------------------------------------------------------------------

typedef short bshort8 __attribute__((ext_vector_type(8)));
typedef unsigned short u16x8 __attribute__((ext_vector_type(8)));
typedef float f32x4  __attribute__((ext_vector_type(4)));

#define AS1 __attribute__((address_space(1)))
#define AS3 __attribute__((address_space(3)))

#define B_   8
#define N_   1024
#define C_   768
#define MT   8192      /* B_*N_ rows per tensor  */
#define M6   49152     /* 6 tensors stacked      */

// ---- workspace layout (bytes) ----
#define OFF_QKNORM   0ull            /* 49152 f32 row sqnorms of qk            */
#define OFF_MAPS     196608ull       /* 49152 f32 attention maps (6 x 8192)    */
#define OFF_STATS    393216ull       /* 15 slabs x 4 x 8192 f32 row/col sums   */
#define OFF_WBUF     2359296ull      /* 15 slabs x 2 x 8192 f32 weights        */
#define OFF_MM       3342336ull      /* 15 min + 15 max (u32 bits)             */
#define MEMSET_BYTES 3342464ull
#define OFF_WTPROJ   3342592ull      /* 1536x768 bf16 (proj_W^T)               */
#define OFF_WTFC1    5701888ull      /* 3072x768 bf16 (fc1_W^T)                */
#define OFF_WTFC2    10420480ull     /* 768x3072 bf16 (fc2_W^T)                */
#define OFF_LNBF     15139072ull     /* 49152x768 bf16 LN1 output              */
#define OFF_QKBF     90636544ull     /* 49152x768 bf16 qk (later reused as xh) */
#define OFF_XHBF     OFF_QKBF        /* alias: qk dead before combine          */
#define OFF_VBF      166134016ull    /* 49152x768 bf16 v                       */
#define OFF_DBUF     241631488ull    /* 8 slabs x 8x1024x1024 bf16 D (134 MB)  */
#define OFF_H1BF     OFF_DBUF        /* alias: FFN intermediate (151 MB chunk) */
// peak: 241631488 + 150994944 = 392,626,432 bytes (<= proven 409 MB ws)

// slab tables: D[i over SU][j over SV]; 0..2 are S_p slabs, 3..14 cross slabs.
__constant__ int cSU[15] = {1,3,5, 2,3,4,5, 2,3,4,5, 4,5,4,5};
__constant__ int cSV[15] = {0,2,4, 0,0,0,0, 1,1,1,1, 2,2,3,3};
__constant__ int cTA[15] = {0,0,0, 1,1,2,2, 1,1,2,2, 2,2,2,2};
__constant__ int cTB[15] = {0,0,0, 1,1,1,1, 1,1,1,1, 2,2,2,2};

__device__ __forceinline__ void gll16(const void* g, void* l) {
    __builtin_amdgcn_global_load_lds((const AS1 unsigned int*)g,
                                     (AS3 unsigned int*)l, 16, 0, 0);
}
__device__ __forceinline__ unsigned short f2bu(float v) {
    __hip_bfloat16 h = __float2bfloat16(v);
    return *reinterpret_cast<unsigned short*>(&h);
}
__device__ __forceinline__ float bu2f(unsigned short u) {
    __hip_bfloat16 h;
    *reinterpret_cast<unsigned short*>(&h) = u;
    return __bfloat162float(h);
}
// XCD-chunked bijective swizzle (nwg % 8 == 0 at all call sites).
__device__ __forceinline__ int xcd_swz(int flat, int nwg) {
    return (flat & 7) * (nwg >> 3) + (flat >> 3);
}

// ---------------------------------------------------------------------------
// 256x256 bf16 NT GEMM core, BK=64, 512 threads = 8 waves (2M x 4N),
// per-wave output 128x64 via acc[8][4] mfma_16x16x32_bf16.
// 2-phase ping-pong LDS (2 x (A 32K | B 32K) = 128 KiB): per K-tile ONE
// __syncthreads (vmcnt+lgkm drain) amortized over 64 MFMA/wave.
// LDS k-chunks XOR-swizzled by row (pre-swizzled GLOBAL source, linear LDS
// dest as global_load_lds requires; ds_read applies same involution).
// ---------------------------------------------------------------------------
__device__ __forceinline__ void gemm256_core(const __hip_bfloat16* __restrict__ A,
                                             const __hip_bfloat16* __restrict__ Bt,
                                             int lda, int ldb, int kTiles,
                                             char* smem, f32x4 acc[8][4])
{
    const int tid = threadIdx.x;
    const int L   = tid & 63;
    const int m   = L & 15, q = L >> 4;
    const int w   = tid >> 6;
    const int wm  = w >> 2, wn = w & 3;

    // staging: 4 A-chunks + 4 B-chunks (16B) per thread per K-tile.
    // linear LDS chunk c = tid + 512*i -> row = c>>3, slot = c&7,
    // global k-chunk gk = slot ^ (row&7)   (bank-spread involution)
    const char* gA[4]; const char* gB[4];
    int lA[4], lB[4];
#pragma unroll
    for (int i = 0; i < 4; ++i) {
        int c  = tid + 512 * i;
        int r  = c >> 3;
        int gk = (c & 7) ^ (r & 7);
        gA[i] = (const char*)(A  + (size_t)r * lda) + gk * 16;
        gB[i] = (const char*)(Bt + (size_t)r * ldb) + gk * 16;
        lA[i] = c * 16;
        lB[i] = 32768 + c * 16;
    }
    const int aBase = wm * 16384 + m * 128;           // (wm*128 + m)*128 bytes
    const int bBase = 32768 + wn * 8192 + m * 128;    // (wn*64 + m)*128 bytes
    const int s0    = (q ^ (m & 7)) * 16;             // swizzled 16B slot

    f32x4 z = {0.f, 0.f, 0.f, 0.f};
#pragma unroll
    for (int i = 0; i < 8; ++i)
#pragma unroll
        for (int j = 0; j < 4; ++j) acc[i][j] = z;

    // prologue: tile 0 -> buf0
#pragma unroll
    for (int i = 0; i < 4; ++i) { gll16(gA[i], smem + lA[i]); gll16(gB[i], smem + lB[i]); }

    for (int kt = 0; kt < kTiles; ++kt) {
        __syncthreads();                       // tile kt ready; prior reads of nxt done
        char* cur = smem + (kt & 1) * 65536;
        if (kt + 1 < kTiles) {
            char* nxt = smem + ((kt + 1) & 1) * 65536;
            const int adv = (kt + 1) * 128;    // +64 bf16 per K-tile
#pragma unroll
            for (int i = 0; i < 4; ++i) {
                gll16(gA[i] + adv, nxt + lA[i]);
                gll16(gB[i] + adv, nxt + lB[i]);
            }
        }
#pragma unroll
        for (int ks = 0; ks < 2; ++ks) {
            const int so = s0 ^ (ks * 64);     // slot ^= 4 per k-slot
            bshort8 af[8], bf[4];
#pragma unroll
            for (int mi = 0; mi < 8; ++mi)
                af[mi] = *(const bshort8*)(cur + aBase + mi * 2048 + so);
#pragma unroll
            for (int nj = 0; nj < 4; ++nj)
                bf[nj] = *(const bshort8*)(cur + bBase + nj * 2048 + so);
#pragma unroll
            for (int mi = 0; mi < 8; ++mi)
#pragma unroll
                for (int nj = 0; nj < 4; ++nj)
                    acc[mi][nj] = __builtin_amdgcn_mfma_f32_16x16x32_bf16(af[mi], bf[nj], acc[mi][nj], 0, 0, 0);
        }
    }
}

// ---------------------------------------------------------------------------
// transpose f32 (R x C) -> bf16 (C x R)
// ---------------------------------------------------------------------------
__global__ __launch_bounds__(256) void transpose_conv(const float* __restrict__ in,
                                                      __hip_bfloat16* __restrict__ out,
                                                      int R, int C)
{
    __shared__ float tile[32][33];
    int bx = blockIdx.x * 32, by = blockIdx.y * 32;
    int tx = threadIdx.x, ty = threadIdx.y;
#pragma unroll
    for (int i = 0; i < 32; i += 8)
        tile[ty + i][tx] = in[(size_t)(by + ty + i) * C + bx + tx];
    __syncthreads();
#pragma unroll
    for (int i = 0; i < 32; i += 8)
        out[(size_t)(bx + ty + i) * R + by + tx] = __float2bfloat16(tile[tx][ty + i]);
}

__global__ void init_mm(unsigned int* mm)
{
    int i = threadIdx.x;
    if (i < 15) { mm[i] = 0x7f800000u; mm[15 + i] = 0u; }
}

// ---------------------------------------------------------------------------
// LN1: wave per row, float4 loads, ushort4 bf16 stores
// ---------------------------------------------------------------------------
__global__ __launch_bounds__(256) void ln1_kernel(const float* __restrict__ anchor,
                                                  const float* __restrict__ positive,
                                                  const float* __restrict__ neg1,
                                                  const float* __restrict__ neg2,
                                                  const float* __restrict__ w1,
                                                  const float* __restrict__ b1,
                                                  __hip_bfloat16* __restrict__ lnbf)
{
    int w = threadIdx.x >> 6, L = threadIdx.x & 63;
    int r = blockIdx.x * 4 + w;
    int t = r >> 13, within = r & 8191;
    const float* src;
    if      (t == 0) src = anchor   + (size_t)within * C_;
    else if (t == 1) src = positive + (size_t)within * C_;
    else if (t <  4) src = neg1 + ((size_t)(t - 2) * MT + within) * C_;
    else             src = neg2 + ((size_t)(t - 4) * MT + within) * C_;
    float4 x[3]; float s = 0.f, sq = 0.f;
#pragma unroll
    for (int j = 0; j < 3; ++j) {
        x[j] = *(const float4*)(src + 4 * L + 256 * j);
        s  += x[j].x + x[j].y + x[j].z + x[j].w;
        sq += x[j].x*x[j].x + x[j].y*x[j].y + x[j].z*x[j].z + x[j].w*x[j].w;
    }
#pragma unroll
    for (int o = 1; o < 64; o <<= 1) { s += __shfl_xor(s, o, 64); sq += __shfl_xor(sq, o, 64); }
    float mu  = s * (1.f / 768.f);
    float var = sq * (1.f / 768.f) - mu * mu;
    float rs  = rsqrtf(var + 1e-5f);
    __hip_bfloat16* dst = lnbf + (size_t)r * C_;
#pragma unroll
    for (int j = 0; j < 3; ++j) {
        int c = 4 * L + 256 * j;
        float4 wv = *(const float4*)(w1 + c);
        float4 bv = *(const float4*)(b1 + c);
        ushort4 o;
        o.x = f2bu((x[j].x - mu) * rs * wv.x + bv.x);
        o.y = f2bu((x[j].y - mu) * rs * wv.y + bv.y);
        o.z = f2bu((x[j].z - mu) * rs * wv.z + bv.z);
        o.w = f2bu((x[j].w - mu) * rs * wv.w + bv.w);
        *(ushort4*)(dst + c) = o;
    }
}

// ---------------------------------------------------------------------------
// proj GEMM (256^2 core): ln_bf @ Wt_proj^T -> qk_bf | v_bf (+bias, +qknorm)
// grid (6, 192) flattened + XCD swizzle.
// ---------------------------------------------------------------------------
__global__ __launch_bounds__(512, 2) void gemm_proj(const __hip_bfloat16* __restrict__ A,
                                                    const __hip_bfloat16* __restrict__ Wt,
                                                    const float* __restrict__ bias,
                                                    __hip_bfloat16* __restrict__ qkbf,
                                                    __hip_bfloat16* __restrict__ vbf,
                                                    float* __restrict__ qknorm)
{
    __shared__ __align__(16) char smem[131072];
    int flat = blockIdx.x + 6 * blockIdx.y;
    int sf   = xcd_swz(flat, 6 * 192);
    int bx = sf % 6, by = sf / 6;
    f32x4 acc[8][4];
    gemm256_core(A + (size_t)by * 256 * C_, Wt + (size_t)bx * 256 * C_,
                 C_, C_, 12, smem, acc);
    int tid = threadIdx.x, w = tid >> 6, L = tid & 63, m = L & 15, q = L >> 4;
    int wm = w >> 2, wn = w & 3;
    int rowBase = by * 256 + wm * 128;
    int colBase = bx * 256 + wn * 64;
    bool isQK = (bx < 3);
    float bv[4];
#pragma unroll
    for (int nj = 0; nj < 4; ++nj) bv[nj] = bias[colBase + nj * 16 + m];
#pragma unroll
    for (int mi = 0; mi < 8; ++mi) {
#pragma unroll
        for (int r = 0; r < 4; ++r) {
            int row = rowBase + mi * 16 + 4 * q + r;
            float sqsum = 0.f;
#pragma unroll
            for (int nj = 0; nj < 4; ++nj) {
                int col = colBase + nj * 16 + m;
                float val = acc[mi][nj][r] + bv[nj];
                if (isQK) {
                    qkbf[(size_t)row * C_ + col] = __float2bfloat16(val);
                    sqsum += val * val;
                } else {
                    vbf[(size_t)row * C_ + (col - C_)] = __float2bfloat16(val);
                }
            }
            if (isQK) {
#pragma unroll
                for (int o = 1; o < 16; o <<= 1) sqsum += __shfl_xor(sqsum, o, 64);
                if (m == 0) atomicAdd(qknorm + row, sqsum);
            }
        }
    }
}

// ---------------------------------------------------------------------------
// gram/D kernel (256^2 core): D = sqrt(max(na+nb-2*G,1e-12)); stores D in the
// SAME blocked fragment layout as before (wsum unchanged) + fused pass-1
// reductions. grid (16 tiles, 8 batches, nslabs), XCD-swizzled.
// Blocked D contract (ushort units), per old 128^2 tile geometry:
//   addr = tile128*16384 + wq*4096 + (s*2+tp)*512 + m*32 + q*8 + (t&1)*4 + r
//   tile128 = (TI*2+wm)*8 + TJ*2 + (wn>>1); wq = ((mi>>2)<<1)|(wn&1);
//   s = mi&3; t = nj.
// ---------------------------------------------------------------------------
__global__ __launch_bounds__(512, 2) void gram_kernel(const __hip_bfloat16* __restrict__ qkbf,
                                                      const float* __restrict__ qknorm,
                                                      __hip_bfloat16* __restrict__ Dbuf,
                                                      float* __restrict__ stats,
                                                      unsigned int* __restrict__ mm,
                                                      int sb)
{
    __shared__ __align__(16) char smem[131072];
    int flat = blockIdx.x + 16 * blockIdx.y + 128 * blockIdx.z;
    int nwg  = 128 * gridDim.z;
    int sf   = xcd_swz(flat, nwg);
    int tile = sf & 15;
    int b    = (sf >> 4) & 7;
    int z    = sf >> 7;
    int slab = sb + z;
    int TI = tile >> 2, TJ = tile & 3;
    int u = cSU[slab], v = cSV[slab];

    const __hip_bfloat16* Ab = qkbf + (size_t)(u * MT + b * N_ + TI * 256) * C_;
    const __hip_bfloat16* Bb = qkbf + (size_t)(v * MT + b * N_ + TJ * 256) * C_;
    f32x4 acc[8][4];
    gemm256_core(Ab, Bb, C_, C_, 12, smem, acc);

    int tid = threadIdx.x, w = tid >> 6, L = tid & 63, m = L & 15, q = L >> 4;
    int wm = w >> 2, wn = w & 3;
    int rowBase = TI * 256 + wm * 128;
    int colBase = TJ * 256 + wn * 64;
    const float* nu = qknorm + u * MT + b * N_;
    const float* nv = qknorm + v * MT + b * N_;
    float nbv[4];
#pragma unroll
    for (int nj = 0; nj < 4; ++nj) nbv[nj] = nv[colBase + nj * 16 + m];

    unsigned short* Dz = (unsigned short*)Dbuf + (size_t)z * 8388608ull + ((size_t)b << 20);
    int tile128 = (TI * 2 + wm) * 8 + TJ * 2 + (wn >> 1);
    float* rs1 = stats + (size_t)slab * 32768;
    float* rs2 = rs1 + 8192;
    float* cs1 = rs1 + 16384;
    float* cs2 = rs1 + 24576;

    float dmin = 3.0e38f, dmax = 0.f;
    float col1[4] = {0.f,0.f,0.f,0.f}, col2[4] = {0.f,0.f,0.f,0.f};
#pragma unroll
    for (int mi = 0; mi < 8; ++mi) {
        float na[4];
#pragma unroll
        for (int r = 0; r < 4; ++r) na[r] = nu[rowBase + mi * 16 + 4 * q + r];
        float dv[4][4];          // [nj][r]
        float h1v[4] = {0.f,0.f,0.f,0.f}, h2v[4] = {0.f,0.f,0.f,0.f};
#pragma unroll
        for (int nj = 0; nj < 4; ++nj) {
#pragma unroll
            for (int r = 0; r < 4; ++r) {
                float d = sqrtf(fmaxf(na[r] + nbv[nj] - 2.f * acc[mi][nj][r], 1e-12f));
                dv[nj][r] = d;
                h1v[r] += d; h2v[r] += d * d;
                col1[nj] += d; col2[nj] += d * d;
                dmin = fminf(dmin, d); dmax = fmaxf(dmax, d);
            }
        }
        // blocked coalesced D store (contract identical to previous layout)
        unsigned short* base = Dz + (size_t)tile128 * 16384
                             + (((mi >> 2) << 1) | (wn & 1)) * 4096
                             + ((mi & 3) * 2) * 512 + m * 32 + q * 8;
#pragma unroll
        for (int tp = 0; tp < 2; ++tp) {
            u16x8 pk;
#pragma unroll
            for (int e = 0; e < 8; ++e)
                pk[e] = f2bu(dv[2 * tp + (e >> 2)][e & 3]);
            *(u16x8*)(base + tp * 512) = pk;
        }
        // row sums (reduce over m within each 16-lane group)
#pragma unroll
        for (int r = 0; r < 4; ++r) {
            float h1 = h1v[r], h2 = h2v[r];
#pragma unroll
            for (int o = 1; o < 16; o <<= 1) { h1 += __shfl_xor(h1, o, 64); h2 += __shfl_xor(h2, o, 64); }
            if (m == 0) {
                int row = rowBase + mi * 16 + 4 * q + r;
                atomicAdd(rs1 + b * N_ + row, h1);
                atomicAdd(rs2 + b * N_ + row, h2);
            }
        }
    }
#pragma unroll
    for (int nj = 0; nj < 4; ++nj) {
        float c1 = col1[nj], c2 = col2[nj];
        c1 += __shfl_xor(c1, 16, 64); c1 += __shfl_xor(c1, 32, 64);
        c2 += __shfl_xor(c2, 16, 64); c2 += __shfl_xor(c2, 32, 64);
        if (q == 0) {
            int col = colBase + nj * 16 + m;
            atomicAdd(cs1 + b * N_ + col, c1);
            atomicAdd(cs2 + b * N_ + col, c2);
        }
    }
#pragma unroll
    for (int o = 1; o < 64; o <<= 1) {
        dmin = fminf(dmin, __shfl_xor(dmin, o, 64));
        dmax = fmaxf(dmax, __shfl_xor(dmax, o, 64));
    }
    if (L == 0) {
        atomicMin(mm + slab, __float_as_uint(dmin));
        atomicMax(mm + 15 + slab, __float_as_uint(dmax));
    }
}

// ---------------------------------------------------------------------------
// weights kernel: unchanged
// ---------------------------------------------------------------------------
__global__ __launch_bounds__(256) void weights_kernel(const float* __restrict__ stats,
                                                      const unsigned int* __restrict__ mm,
                                                      float* __restrict__ wbuf,
                                                      float* __restrict__ maps,
                                                      const float* __restrict__ theta,
                                                      const float* __restrict__ alpha,
                                                      int sb)
{
    int job = blockIdx.x, b = blockIdx.y;
    int slab = sb + (job >> 1);
    int useB = job & 1;
    const float* s1 = stats + (size_t)slab * 32768 + useB * 16384;
    const float* s2 = s1 + 8192;
    int type = useB ? cTB[slab] : cTA[slab];
    int dst  = useB ? cSU[slab] : cSV[slab];
    float off = (type == 0) ? __uint_as_float(mm[15 + slab]) : __uint_as_float(mm[slab]);
    float k  = tanhf(theta[0]) + 1.0f;
    float al = 1.0f / (1.0f + expf(-alpha[0]));
    float cf = (type == 0) ? -1.0f : ((type == 1) ? 0.5f * k * al : 0.5f * k * (1.0f - al));
    float* wout = wbuf + (size_t)slab * 16384 + useB * 8192 + b * N_;

    float sumw = 0.f;
    for (int i = threadIdx.x; i < N_; i += 256) {
        float a1 = s1[b * N_ + i], a2 = s2[b * N_ + i];
        float nrm2  = fmaxf(a2 - 2.f * off * a1 + (float)N_ * off * off, 0.f);
        float denom = fmaxf(sqrtf(nrm2), 1e-12f);
        float wv = cf / denom;
        wout[i] = wv;
        sumw += wv;
    }
    int w = threadIdx.x >> 6, L = threadIdx.x & 63;
#pragma unroll
    for (int o = 1; o < 64; o <<= 1) sumw += __shfl_xor(sumw, o, 64);
    __shared__ float red[4];
    if (L == 0) red[w] = sumw;
    __syncthreads();
    float tot = red[0] + red[1] + red[2] + red[3];
    float Cb = -off * tot;
    for (int j = threadIdx.x; j < N_; j += 256)
        atomicAdd(maps + (size_t)dst * MT + b * N_ + j, Cb);
}

// ---------------------------------------------------------------------------
// weighted-sum pass over blocked bf16 D: unchanged (layout contract held)
// ---------------------------------------------------------------------------
__global__ __launch_bounds__(256) void wsum_kernel(const __hip_bfloat16* __restrict__ Dbuf,
                                                   const float* __restrict__ wbuf,
                                                   float* __restrict__ maps,
                                                   int sb)
{
    int z = blockIdx.z, slab = sb + z, b = blockIdx.y;
    int tile = blockIdx.x;
    int ti = tile >> 3, tj = tile & 7;
    int u = cSU[slab], v = cSV[slab];
    int tid = threadIdx.x, w = tid >> 6, L = tid & 63, m = L & 15, q = L >> 4;
    const unsigned short* Dc = (const unsigned short*)Dbuf + (size_t)z * 8388608ull
                               + ((size_t)b << 20) + (size_t)tile * 16384 + w * 4096;
    const float* wr = wbuf + (size_t)slab * 16384 + b * N_ + ti * 128;
    const float* wc = wbuf + (size_t)slab * 16384 + 8192 + b * N_ + tj * 128;

    __shared__ float swr[128], swc[128];
    if (threadIdx.x < 128) swr[threadIdx.x] = wr[threadIdx.x];
    else                   swc[threadIdx.x - 128] = wc[threadIdx.x - 128];
    __syncthreads();

    int wrbase = (w >> 1) * 64, wcbase = (w & 1) * 64;
    float wc1[4];
#pragma unroll
    for (int t = 0; t < 4; ++t) wc1[t] = swc[wcbase + 16 * t + m];
    float wr4[4][4];
#pragma unroll
    for (int s = 0; s < 4; ++s)
#pragma unroll
        for (int r = 0; r < 4; ++r) wr4[s][r] = swr[wrbase + 16 * s + 4 * q + r];

    float rowacc[4][4];
#pragma unroll
    for (int s = 0; s < 4; ++s)
#pragma unroll
        for (int r = 0; r < 4; ++r) rowacc[s][r] = 0.f;
    float colacc[4] = {0.f,0.f,0.f,0.f};

#pragma unroll
    for (int s = 0; s < 4; ++s) {
#pragma unroll
        for (int tp = 0; tp < 2; ++tp) {
            u16x8 d8 = *(const u16x8*)(Dc + (s * 2 + tp) * 512 + m * 32 + q * 8);
#pragma unroll
            for (int e = 0; e < 8; ++e) {
                int t = 2 * tp + (e >> 2), r = e & 3;
                float d = bu2f(d8[e]);
                rowacc[s][r] += wc1[t] * d;
                colacc[t]    += wr4[s][r] * d;
            }
        }
    }
#pragma unroll
    for (int s = 0; s < 4; ++s)
#pragma unroll
        for (int r = 0; r < 4; ++r) {
            float h = rowacc[s][r];
#pragma unroll
            for (int o = 1; o < 16; o <<= 1) h += __shfl_xor(h, o, 64);
            if (m == 0)
                atomicAdd(maps + (size_t)u * MT + b * N_ + ti * 128 + wrbase + 16 * s + 4 * q + r, h);
        }
#pragma unroll
    for (int t = 0; t < 4; ++t) {
        float c = colacc[t];
        c += __shfl_xor(c, 16, 64); c += __shfl_xor(c, 32, 64);
        if (q == 0)
            atomicAdd(maps + (size_t)v * MT + b * N_ + tj * 128 + wcbase + 16 * t + m, c);
    }
}

// ---------------------------------------------------------------------------
// combine + LN2: unchanged
// ---------------------------------------------------------------------------
__global__ __launch_bounds__(256) void combine_ln2(const float* __restrict__ maps,
                                                   const __hip_bfloat16* __restrict__ vbf,
                                                   const __hip_bfloat16* __restrict__ lnbf,
                                                   const float* __restrict__ w2,
                                                   const float* __restrict__ b2,
                                                   float* __restrict__ dout,
                                                   __hip_bfloat16* __restrict__ xhbf)
{
    int w = threadIdx.x >> 6, L = threadIdx.x & 63;
    int r = blockIdx.x * 4 + w;
    int t = r >> 13;
    float mv = maps[r];
    const __hip_bfloat16* vp = vbf + (size_t)r * C_;
    const __hip_bfloat16* lp = lnbf + (size_t)r * C_;
    float x[12]; float s = 0.f, sq = 0.f;
#pragma unroll
    for (int j = 0; j < 3; ++j) {
        int c = 4 * L + 256 * j;
        ushort4 vv = *(const ushort4*)(vp + c);
        ushort4 ll = *(const ushort4*)(lp + c);
        float xv[4];
        xv[0] = (t < 2) ? (mv * bu2f(vv.x) + bu2f(ll.x)) : (mv * bu2f(vv.x) * bu2f(ll.x));
        xv[1] = (t < 2) ? (mv * bu2f(vv.y) + bu2f(ll.y)) : (mv * bu2f(vv.y) * bu2f(ll.y));
        xv[2] = (t < 2) ? (mv * bu2f(vv.z) + bu2f(ll.z)) : (mv * bu2f(vv.z) * bu2f(ll.z));
        xv[3] = (t < 2) ? (mv * bu2f(vv.w) + bu2f(ll.w)) : (mv * bu2f(vv.w) * bu2f(ll.w));
        float4 xo = {xv[0], xv[1], xv[2], xv[3]};
        *(float4*)(dout + (size_t)r * C_ + c) = xo;
#pragma unroll
        for (int e = 0; e < 4; ++e) { x[4*j+e] = xv[e]; s += xv[e]; sq += xv[e]*xv[e]; }
    }
#pragma unroll
    for (int o = 1; o < 64; o <<= 1) { s += __shfl_xor(s, o, 64); sq += __shfl_xor(sq, o, 64); }
    float mu  = s * (1.f / 768.f);
    float var = sq * (1.f / 768.f) - mu * mu;
    float rs  = rsqrtf(var + 1e-5f);
    __hip_bfloat16* dst = xhbf + (size_t)r * C_;
#pragma unroll
    for (int j = 0; j < 3; ++j) {
        int c = 4 * L + 256 * j;
        float4 wv = *(const float4*)(w2 + c);
        float4 bv = *(const float4*)(b2 + c);
        ushort4 o;
        o.x = f2bu((x[4*j+0] - mu) * rs * wv.x + bv.x);
        o.y = f2bu((x[4*j+1] - mu) * rs * wv.y + bv.y);
        o.z = f2bu((x[4*j+2] - mu) * rs * wv.z + bv.z);
        o.w = f2bu((x[4*j+3] - mu) * rs * wv.w + bv.w);
        *(ushort4*)(dst + c) = o;
    }
}

// ---------------------------------------------------------------------------
// FFN1 (256^2 core): xh @ fc1^T + b -> gelu(exact) -> bf16
// ---------------------------------------------------------------------------
__global__ __launch_bounds__(512, 2) void gemm_ffn1(const __hip_bfloat16* __restrict__ A,
                                                    const __hip_bfloat16* __restrict__ Wt,
                                                    const float* __restrict__ bias,
                                                    __hip_bfloat16* __restrict__ h1)
{
    __shared__ __align__(16) char smem[131072];
    int flat = blockIdx.x + 12 * blockIdx.y;
    int sf   = xcd_swz(flat, 12 * 96);
    int bx = sf % 12, by = sf / 12;
    f32x4 acc[8][4];
    gemm256_core(A + (size_t)by * 256 * C_, Wt + (size_t)bx * 256 * C_,
                 C_, C_, 12, smem, acc);
    int tid = threadIdx.x, w = tid >> 6, L = tid & 63, m = L & 15, q = L >> 4;
    int wm = w >> 2, wn = w & 3;
    int rowBase = by * 256 + wm * 128;
    int colBase = bx * 256 + wn * 64;
    float bv[4];
#pragma unroll
    for (int nj = 0; nj < 4; ++nj) bv[nj] = bias[colBase + nj * 16 + m];
#pragma unroll
    for (int mi = 0; mi < 8; ++mi)
#pragma unroll
        for (int r = 0; r < 4; ++r) {
            int row = rowBase + mi * 16 + 4 * q + r;
#pragma unroll
            for (int nj = 0; nj < 4; ++nj) {
                int col = colBase + nj * 16 + m;
                float val = acc[mi][nj][r] + bv[nj];
                float ge  = 0.5f * val * (1.0f + erff(val * 0.70710678118654752f));
                h1[(size_t)row * 3072 + col] = __float2bfloat16(ge);
            }
        }
}

// ---------------------------------------------------------------------------
// FFN2 (256^2 core): h1 @ fc2^T + b, accumulated into d_out
// ---------------------------------------------------------------------------
__global__ __launch_bounds__(512, 2) void gemm_ffn2(const __hip_bfloat16* __restrict__ A,
                                                    const __hip_bfloat16* __restrict__ Wt,
                                                    const float* __restrict__ bias,
                                                    float* __restrict__ out)
{
    __shared__ __align__(16) char smem[131072];
    int flat = blockIdx.x + 3 * blockIdx.y;
    int sf   = xcd_swz(flat, 3 * 96);
    int bx = sf % 3, by = sf / 3;
    f32x4 acc[8][4];
    gemm256_core(A + (size_t)by * 256 * 3072, Wt + (size_t)bx * 256 * 3072,
                 3072, 3072, 48, smem, acc);
    int tid = threadIdx.x, w = tid >> 6, L = tid & 63, m = L & 15, q = L >> 4;
    int wm = w >> 2, wn = w & 3;
    int rowBase = by * 256 + wm * 128;
    int colBase = bx * 256 + wn * 64;
    float bv[4];
#pragma unroll
    for (int nj = 0; nj < 4; ++nj) bv[nj] = bias[colBase + nj * 16 + m];
#pragma unroll
    for (int mi = 0; mi < 8; ++mi)
#pragma unroll
        for (int r = 0; r < 4; ++r) {
            int row = rowBase + mi * 16 + 4 * q + r;
#pragma unroll
            for (int nj = 0; nj < 4; ++nj) {
                int col = colBase + nj * 16 + m;
                size_t idx = (size_t)row * C_ + col;
                out[idx] = out[idx] + acc[mi][nj][r] + bv[nj];
            }
        }
}

// ---------------------------------------------------------------------------
extern "C" void kernel_launch(void* const* d_in, const int* in_sizes, int n_in,
                              void* d_out, int out_size, void* d_ws, size_t ws_size,
                              hipStream_t stream)
{
    (void)in_sizes; (void)n_in; (void)out_size; (void)ws_size;
    const float* anchor   = (const float*)d_in[0];
    const float* positive = (const float*)d_in[1];
    const float* neg1     = (const float*)d_in[2];
    const float* neg2     = (const float*)d_in[3];
    const float* n1w      = (const float*)d_in[4];
    const float* n1b      = (const float*)d_in[5];
    const float* n2w      = (const float*)d_in[6];
    const float* n2b      = (const float*)d_in[7];
    const float* projW    = (const float*)d_in[8];
    const float* projb    = (const float*)d_in[9];
    const float* fc1W     = (const float*)d_in[10];
    const float* fc1b     = (const float*)d_in[11];
    const float* fc2W     = (const float*)d_in[12];
    const float* fc2b     = (const float*)d_in[13];
    const float* theta    = (const float*)d_in[14];
    const float* alpha    = (const float*)d_in[15];
    float* dout = (float*)d_out;

    char* ws = (char*)d_ws;
    float*          qknorm = (float*)(ws + OFF_QKNORM);
    float*          maps   = (float*)(ws + OFF_MAPS);
    float*          stats  = (float*)(ws + OFF_STATS);
    float*          wbuf   = (float*)(ws + OFF_WBUF);
    unsigned int*   mm     = (unsigned int*)(ws + OFF_MM);
    __hip_bfloat16* WtProj = (__hip_bfloat16*)(ws + OFF_WTPROJ);
    __hip_bfloat16* WtFc1  = (__hip_bfloat16*)(ws + OFF_WTFC1);
    __hip_bfloat16* WtFc2  = (__hip_bfloat16*)(ws + OFF_WTFC2);
    __hip_bfloat16* lnbf   = (__hip_bfloat16*)(ws + OFF_LNBF);
    __hip_bfloat16* qkbf   = (__hip_bfloat16*)(ws + OFF_QKBF);
    __hip_bfloat16* xhbf   = (__hip_bfloat16*)(ws + OFF_XHBF);
    __hip_bfloat16* vbf    = (__hip_bfloat16*)(ws + OFF_VBF);
    __hip_bfloat16* Dbuf   = (__hip_bfloat16*)(ws + OFF_DBUF);
    __hip_bfloat16* h1bf   = (__hip_bfloat16*)(ws + OFF_H1BF);

    hipMemsetAsync(ws, 0, MEMSET_BYTES, stream);
    init_mm<<<1, 64, 0, stream>>>(mm);

    transpose_conv<<<dim3(48, 24), dim3(32, 8), 0, stream>>>(projW, WtProj, 768, 1536);
    transpose_conv<<<dim3(96, 24), dim3(32, 8), 0, stream>>>(fc1W,  WtFc1,  768, 3072);
    transpose_conv<<<dim3(24, 96), dim3(32, 8), 0, stream>>>(fc2W,  WtFc2,  3072, 768);

    ln1_kernel<<<12288, 256, 0, stream>>>(anchor, positive, neg1, neg2, n1w, n1b, lnbf);

    gemm_proj<<<dim3(6, 192), 512, 0, stream>>>(lnbf, WtProj, projb, qkbf, vbf, qknorm);

    for (int g = 0; g < 2; ++g) {
        int sb = g * 8;
        int ns = g ? 7 : 8;
        gram_kernel<<<dim3(16, 8, ns), 512, 0, stream>>>(qkbf, qknorm, Dbuf, stats, mm, sb);
        weights_kernel<<<dim3(2 * ns, 8), 256, 0, stream>>>(stats, mm, wbuf, maps, theta, alpha, sb);
        wsum_kernel<<<dim3(64, 8, ns), 256, 0, stream>>>(Dbuf, wbuf, maps, sb);
    }

    combine_ln2<<<12288, 256, 0, stream>>>(maps, vbf, lnbf, n2w, n2b, dout, xhbf);

    for (int ch = 0; ch < 2; ++ch) {
        size_t ro = (size_t)ch * 24576;
        gemm_ffn1<<<dim3(12, 96), 512, 0, stream>>>(xhbf + ro * C_, WtFc1, fc1b, h1bf);
        gemm_ffn2<<<dim3(3, 96), 512, 0, stream>>>(h1bf, WtFc2, fc2b, dout + ro * C_);
    }
}